// Round 5
// baseline (612.988 us; speedup 1.0000x reference)
//
#include <hip/hip_runtime.h>

#define B_  2
#define S_  2048
#define D_  1024
#define H_  16
#define DH_ 64
#define BH_ (B_*H_)
#define NT_ (S_/64)
#define QSCALE 46.1662413084f   /* 32 * log2(e): exp2-domain softmax */

using f32x4   = __attribute__((ext_vector_type(4))) float;
using short4v = __attribute__((ext_vector_type(4))) short;
using short8v = __attribute__((ext_vector_type(8))) short;

// Pre-split inputs (bf16 hi/lo)
__device__ short g_xh[(size_t)B_*S_*D_], g_xl[(size_t)B_*S_*D_];
__device__ short g_wh[(size_t)3*D_*D_],  g_wl[(size_t)3*D_*D_];
// Proj outputs: q*QSCALE and k pre-split hi/lo [bh][s][dh]; v transposed [bh][dh][s].
__device__ short g_qh[(size_t)BH_*S_*DH_];
__device__ short g_ql[(size_t)BH_*S_*DH_];
__device__ short g_kh[(size_t)BH_*S_*DH_];
__device__ short g_kl[(size_t)BH_*S_*DH_];
__device__ short g_vt[(size_t)BH_*DH_*S_];

__device__ __forceinline__ short f2bf(float x){
  unsigned u = __builtin_bit_cast(unsigned, x);
  u += 0x7fffu + ((u >> 16) & 1u);           // RNE
  return (short)(unsigned short)(u >> 16);
}
__device__ __forceinline__ float bf2f(short h){
  return __builtin_bit_cast(float, ((unsigned)(unsigned short)h) << 16);
}

#define MFMA16(A,B,C) __builtin_amdgcn_mfma_f32_16x16x32_bf16((A),(B),(C),0,0,0)

// ---------------------------------------------------------------------------
// Pre-split f32 -> bf16 hi/lo (BW-bound, one pass)
// ---------------------------------------------------------------------------
__global__ __launch_bounds__(256) void split_f32(
    const float* __restrict__ src, short* __restrict__ dh,
    short* __restrict__ dl, int n8)
{
  int i = blockIdx.x * 256 + threadIdx.x;
  const int stride = gridDim.x * 256;
  for (; i < n8; i += stride) {
    float4 a = ((const float4*)src)[2*i];
    float4 b = ((const float4*)src)[2*i + 1];
    float f[8] = {a.x,a.y,a.z,a.w,b.x,b.y,b.z,b.w};
    short8v h, l;
#pragma unroll
    for (int j = 0; j < 8; ++j) {
      short hh = f2bf(f[j]);
      h[j] = hh;
      l[j] = f2bf(f[j] - bf2f(hh));
    }
    ((short8v*)dh)[i] = h;
    ((short8v*)dl)[i] = l;
  }
}

// ---------------------------------------------------------------------------
// QKV projection.  128x128 tile, 4 waves, BK=32. Inputs pre-split bf16, so
// staging = pure 16B loads + ds_write_b128 (no VALU conversion in-loop).
// 3-term split MFMA for Q/K blocks, 1-term for V. Reg-prefetch next K-step.
// Epilogue re-stages C through LDS for coalesced 16B stores.
// ---------------------------------------------------------------------------
__global__ __launch_bounds__(256) void qkv_proj_mfma(const float* __restrict__ bias)
{
  __shared__ short SM[20480];   // 40 KB
  short (*AH )[40] = (short(*)[40])(SM);
  short (*AL )[40] = (short(*)[40])(SM + 5120);
  short (*BHs)[40] = (short(*)[40])(SM + 10240);
  short (*BLs)[40] = (short(*)[40])(SM + 15360);
  short *LT = SM;               // epilogue buffer, pitch 136

  const int tid = threadIdx.x;
  const int w  = tid >> 6;
  const int ln = tid & 15;
  const int g  = (tid & 63) >> 4;
  const int wr = w >> 1, wc = w & 1;
  const int m0 = blockIdx.y * 128;
  const int n0 = blockIdx.x * 128;
  const int which = n0 >> 10;       // 0=q 1=k 2=v

  const int r_  = tid >> 2;             // 0..63   (stage row, rep adds 64)
  const int c8  = (tid & 3) << 3;       // 0,8,16,24

  f32x4 zero4 = {0.f, 0.f, 0.f, 0.f};
  f32x4 acc[4][4];
#pragma unroll
  for (int mf = 0; mf < 4; ++mf)
#pragma unroll
    for (int nf = 0; nf < 4; ++nf) acc[mf][nf] = zero4;

  short8v rAh[2], rAl[2], rBh[2], rBl[2];
#pragma unroll
  for (int rep = 0; rep < 2; ++rep) {
    size_t ao = (size_t)(m0 + 64*rep + r_) * D_ + c8;
    size_t bo = (size_t)(n0 + 64*rep + r_) * D_ + c8;
    rAh[rep] = *(const short8v*)&g_xh[ao];
    rBh[rep] = *(const short8v*)&g_wh[bo];
    if (which < 2) {
      rAl[rep] = *(const short8v*)&g_xl[ao];
      rBl[rep] = *(const short8v*)&g_wl[bo];
    }
  }

  for (int k0 = 0; k0 < D_; k0 += 32) {
#pragma unroll
    for (int rep = 0; rep < 2; ++rep) {
      int r = 64*rep + r_;
      *(short8v*)&AH [r][c8] = rAh[rep];
      *(short8v*)&BHs[r][c8] = rBh[rep];
      if (which < 2) {
        *(short8v*)&AL [r][c8] = rAl[rep];
        *(short8v*)&BLs[r][c8] = rBl[rep];
      }
    }
    __syncthreads();

    if (k0 + 32 < D_) {
#pragma unroll
      for (int rep = 0; rep < 2; ++rep) {
        size_t ao = (size_t)(m0 + 64*rep + r_) * D_ + k0 + 32 + c8;
        size_t bo = (size_t)(n0 + 64*rep + r_) * D_ + k0 + 32 + c8;
        rAh[rep] = *(const short8v*)&g_xh[ao];
        rBh[rep] = *(const short8v*)&g_wh[bo];
        if (which < 2) {
          rAl[rep] = *(const short8v*)&g_xl[ao];
          rBl[rep] = *(const short8v*)&g_wl[bo];
        }
      }
    }

    short8v ah[4], al[4], bhf[4], blf[4];
#pragma unroll
    for (int mf = 0; mf < 4; ++mf) {
      ah[mf] = *(const short8v*)&AH[64*wr + 16*mf + ln][8*g];
      if (which < 2) al[mf] = *(const short8v*)&AL[64*wr + 16*mf + ln][8*g];
    }
#pragma unroll
    for (int nf = 0; nf < 4; ++nf) {
      bhf[nf] = *(const short8v*)&BHs[64*wc + 16*nf + ln][8*g];
      if (which < 2) blf[nf] = *(const short8v*)&BLs[64*wc + 16*nf + ln][8*g];
    }
    __builtin_amdgcn_s_setprio(1);
#pragma unroll
    for (int mf = 0; mf < 4; ++mf)
#pragma unroll
      for (int nf = 0; nf < 4; ++nf) {
        acc[mf][nf] = MFMA16(ah[mf], bhf[nf], acc[mf][nf]);
        if (which < 2) {
          acc[mf][nf] = MFMA16(al[mf], bhf[nf], acc[mf][nf]);
          acc[mf][nf] = MFMA16(ah[mf], blf[nf], acc[mf][nf]);
        }
      }
    __builtin_amdgcn_s_setprio(0);
    __syncthreads();
  }

  // ---- epilogue: bias+scale, then LDS-transpose coalesced stores ----
  const float sc = (which == 0) ? QSCALE : 1.0f;
  float bb[4];
#pragma unroll
  for (int nf = 0; nf < 4; ++nf) bb[nf] = bias[n0 + 64*wc + 16*nf + ln];
#pragma unroll
  for (int mf = 0; mf < 4; ++mf)
#pragma unroll
    for (int nf = 0; nf < 4; ++nf)
#pragma unroll
      for (int i = 0; i < 4; ++i)
        acc[mf][nf][i] = (acc[mf][nf][i] + bb[nf]) * sc;

  const int bidx  = m0 >> 11;
  const int s0    = m0 & 2047;
  const int hbase = (n0 & 1023) >> 6;

  if (which == 2) {
#pragma unroll
    for (int nf = 0; nf < 4; ++nf) {
      int dl = 64*wc + 16*nf + ln;
#pragma unroll
      for (int mf = 0; mf < 4; ++mf) {
        int sl = 64*wr + 16*mf + 4*g;
        short4v v4;
#pragma unroll
        for (int i = 0; i < 4; ++i) v4[i] = f2bf(acc[mf][nf][i]);
        *(short4v*)&LT[dl*136 + sl] = v4;
      }
    }
    __syncthreads();
#pragma unroll
    for (int rep = 0; rep < 8; ++rep) {
      int idx = rep * 256 + tid;
      int r  = idx >> 4;
      int sg = idx & 15;
      short8v v = *(const short8v*)&LT[r*136 + sg*8];
      int h = hbase + (r >> 6), dh = r & 63;
      *(short8v*)&g_vt[(((size_t)(bidx*H_ + h))*DH_ + dh)*S_ + s0 + sg*8] = v;
    }
  } else {
    short* dH = (which == 0) ? g_qh : g_kh;
    short* dL = (which == 0) ? g_ql : g_kl;
#pragma unroll
    for (int mf = 0; mf < 4; ++mf)
#pragma unroll
      for (int nf = 0; nf < 4; ++nf) {
        int dl = 64*wc + 16*nf + ln;
#pragma unroll
        for (int i = 0; i < 4; ++i)
          LT[(64*wr + 16*mf + 4*g + i)*136 + dl] = f2bf(acc[mf][nf][i]);
      }
    __syncthreads();
#pragma unroll
    for (int rep = 0; rep < 8; ++rep) {
      int idx = rep * 256 + tid;
      int r  = idx >> 4;
      int sg = idx & 15;
      short8v v = *(const short8v*)&LT[r*136 + sg*8];
      int h = hbase + (sg >> 3);
      int dh = (sg & 7) * 8;
      *(short8v*)&dH[(((size_t)(bidx*H_ + h))*S_ + s0 + r)*DH_ + dh] = v;
    }
    __syncthreads();
#pragma unroll
    for (int mf = 0; mf < 4; ++mf)
#pragma unroll
      for (int nf = 0; nf < 4; ++nf) {
        int dl = 64*wc + 16*nf + ln;
#pragma unroll
        for (int i = 0; i < 4; ++i) {
          float v = acc[mf][nf][i];
          short hi = f2bf(v);
          LT[(64*wr + 16*mf + 4*g + i)*136 + dl] = f2bf(v - bf2f(hi));
        }
      }
    __syncthreads();
#pragma unroll
    for (int rep = 0; rep < 8; ++rep) {
      int idx = rep * 256 + tid;
      int r  = idx >> 4;
      int sg = idx & 15;
      short8v v = *(const short8v*)&LT[r*136 + sg*8];
      int h = hbase + (sg >> 3);
      int dh = (sg & 7) * 8;
      *(short8v*)&dL[(((size_t)(bidx*H_ + h))*S_ + s0 + r)*DH_ + dh] = v;
    }
  }
}

// ---------------------------------------------------------------------------
// Flash attention. Block = 64 q-rows x (b,h); 4 waves x 16 rows; no barriers.
// Grid 1024 -> 4 blocks/CU. exp2-domain softmax with defer-rescale.
// K/V fragments direct from global (L1/L2-resident); P via swizzled LDS.
// ---------------------------------------------------------------------------
__global__ __launch_bounds__(256, 4) void attn_mfma(float* __restrict__ out)
{
  __shared__ short PS[4][16][64];   // per-wave, XOR-swizzled cols

  const int tid = threadIdx.x;
  const int w  = tid >> 6;
  const int ln = tid & 15;
  const int g  = (tid & 63) >> 4;

  // XCD-chunked swizzle: 1024 blocks; XCD x gets bh in [4x,4x+4).
  const int bid = blockIdx.x;
  const int swz = (bid & 7) * 128 + (bid >> 3);
  const int bh  = swz >> 5;
  const int q0  = (swz & 31) * 64;
  const int b   = bh >> 4, h = bh & 15;

  const size_t qb = (size_t)bh * S_ * DH_;
  const short* __restrict__ Kh = g_kh + qb;
  const short* __restrict__ Kl = g_kl + qb;
  const short* __restrict__ Vt = g_vt + (size_t)bh * DH_ * S_;

  // Q fragments: rows q0+16w+ln, k-slots d = 32ks+8g+j.
  short8v qh[2], ql[2];
#pragma unroll
  for (int ks = 0; ks < 2; ++ks) {
    size_t o = qb + (size_t)(q0 + 16*w + ln) * DH_ + 32*ks + 8*g;
    qh[ks] = *(const short8v*)&g_qh[o];
    ql[ks] = *(const short8v*)&g_ql[o];
  }

  f32x4 zero4 = {0.f,0.f,0.f,0.f};
  f32x4 o_[4];
  float m_[4], l_[4];
#pragma unroll
  for (int nf = 0; nf < 4; ++nf) o_[nf] = zero4;
#pragma unroll
  for (int i = 0; i < 4; ++i) { m_[i] = -1e30f; l_[i] = 0.f; }

  for (int t = 0; t < NT_; ++t) {
    const int t0 = t * 64;

    // ---- K fragments (hi/lo) ----
    short8v kh[2][4], kl[2][4];
#pragma unroll
    for (int ks = 0; ks < 2; ++ks)
#pragma unroll
      for (int nf = 0; nf < 4; ++nf) {
        size_t o = (size_t)(t0 + 16*nf + ln) * DH_ + 32*ks + 8*g;
        kh[ks][nf] = *(const short8v*)&Kh[o];
        kl[ks][nf] = *(const short8v*)&Kl[o];
      }

    // ---- S = Q K^T (scale folded into Q), 3-term split ----
    f32x4 s[4];
#pragma unroll
    for (int nf = 0; nf < 4; ++nf) s[nf] = zero4;
    __builtin_amdgcn_s_setprio(1);
#pragma unroll
    for (int ks = 0; ks < 2; ++ks)
#pragma unroll
      for (int nf = 0; nf < 4; ++nf) {
        s[nf] = MFMA16(qh[ks], kh[ks][nf], s[nf]);
        s[nf] = MFMA16(ql[ks], kh[ks][nf], s[nf]);
        s[nf] = MFMA16(qh[ks], kl[ks][nf], s[nf]);
      }
    __builtin_amdgcn_s_setprio(0);

    // ---- V fragments (issued before softmax; latency hides under VALU) ----
    short8v vb[2][4];
#pragma unroll
    for (int ks = 0; ks < 2; ++ks)
#pragma unroll
      for (int nf = 0; nf < 4; ++nf)
        vb[ks][nf] = *(const short8v*)&Vt[(size_t)(16*nf + ln) * S_ + t0 + 32*ks + 8*g];

    // ---- online softmax (exp2 domain), defer-rescale ----
    float mt[4];
#pragma unroll
    for (int i = 0; i < 4; ++i) {
      float v = fmaxf(fmaxf(s[0][i], s[1][i]), fmaxf(s[2][i], s[3][i]));
      v = fmaxf(v, __shfl_xor(v, 1));
      v = fmaxf(v, __shfl_xor(v, 2));
      v = fmaxf(v, __shfl_xor(v, 4));
      v = fmaxf(v, __shfl_xor(v, 8));
      mt[i] = v;
    }
    bool need = (mt[0] > m_[0]) | (mt[1] > m_[1]) |
                (mt[2] > m_[2]) | (mt[3] > m_[3]);
    if (__any(need)) {
#pragma unroll
      for (int i = 0; i < 4; ++i) {
        float mn = fmaxf(m_[i], mt[i]);
        float corr = exp2f(m_[i] - mn);
        l_[i] *= corr;
        m_[i] = mn;
#pragma unroll
        for (int nf = 0; nf < 4; ++nf) o_[nf][i] *= corr;
      }
    }
#pragma unroll
    for (int i = 0; i < 4; ++i) {
      float sum = 0.f;
      const int row = 4*g + i;
      const int e   = row & 7;
#pragma unroll
      for (int nf = 0; nf < 4; ++nf) {
        float p = exp2f(s[nf][i] - m_[i]);
        sum += p;
        PS[w][row][(16*nf + ln) ^ (e << 3)] = f2bf(p);
      }
      sum += __shfl_xor(sum, 1);
      sum += __shfl_xor(sum, 2);
      sum += __shfl_xor(sum, 4);
      sum += __shfl_xor(sum, 8);
      l_[i] += sum;
    }

    // ---- O += P V ----
    __builtin_amdgcn_s_setprio(1);
#pragma unroll
    for (int ks = 0; ks < 2; ++ks) {
      const short8v pa =
          *(const short8v*)&PS[w][ln][(32*ks + 8*g) ^ ((ln & 7) << 3)];
#pragma unroll
      for (int nf = 0; nf < 4; ++nf)
        o_[nf] = MFMA16(pa, vb[ks][nf], o_[nf]);
    }
    __builtin_amdgcn_s_setprio(0);
  }

  // ---- epilogue ----
#pragma unroll
  for (int i = 0; i < 4; ++i) {
    float inv = 1.0f / l_[i];
    int row = q0 + 16*w + 4*g + i;
    float* op = &out[((size_t)b * S_ + row) * D_ + h * DH_];
#pragma unroll
    for (int nf = 0; nf < 4; ++nf)
      op[16*nf + ln] = o_[nf][i] * inv;
  }
}

extern "C" void kernel_launch(void* const* d_in, const int* in_sizes, int n_in,
                              void* d_out, int out_size, void* d_ws, size_t ws_size,
                              hipStream_t stream) {
    (void)d_ws; (void)ws_size; (void)n_in; (void)in_sizes;
    const float* X    = (const float*)d_in[0];  // query [B,S,D]
    const float* W    = (const float*)d_in[3];  // [3D, D]
    const float* bias = (const float*)d_in[4];  // [3D]
    float* out = (float*)d_out;

    short *xh, *xl, *wh, *wl;
    hipGetSymbolAddress((void**)&xh, HIP_SYMBOL(g_xh));
    hipGetSymbolAddress((void**)&xl, HIP_SYMBOL(g_xl));
    hipGetSymbolAddress((void**)&wh, HIP_SYMBOL(g_wh));
    hipGetSymbolAddress((void**)&wl, HIP_SYMBOL(g_wl));

    split_f32<<<dim3(1024), 256, 0, stream>>>(X, xh, xl, (B_*S_*D_)/8);
    split_f32<<<dim3(1024), 256, 0, stream>>>(W, wh, wl, (3*D_*D_)/8);

    dim3 gProj(24, 32);        // N/128 x M/128
    qkv_proj_mfma<<<gProj, 256, 0, stream>>>(bias);

    attn_mfma<<<dim3(1024), 256, 0, stream>>>(out);
}

// Round 6
// 489.881 us; speedup vs baseline: 1.2513x; 1.2513x over previous
//
#include <hip/hip_runtime.h>

#define B_  2
#define S_  2048
#define D_  1024
#define H_  16
#define DH_ 64
#define BH_ (B_*H_)
#define NKV_ (S_/32)
#define QSCALE 46.1662413084f   /* 32 * log2(e): exp2-domain softmax */

using f32x4   = __attribute__((ext_vector_type(4))) float;
using short4v = __attribute__((ext_vector_type(4))) short;
using short8v = __attribute__((ext_vector_type(8))) short;

// Pre-split inputs (bf16 hi/lo)
__device__ short g_xh[(size_t)B_*S_*D_], g_xl[(size_t)B_*S_*D_];
__device__ short g_wh[(size_t)3*D_*D_],  g_wl[(size_t)3*D_*D_];
// Proj outputs: q*QSCALE and k pre-split hi/lo [bh][s][dh]; v transposed [bh][dh][s].
__device__ short g_qh[(size_t)BH_*S_*DH_];
__device__ short g_ql[(size_t)BH_*S_*DH_];
__device__ short g_kh[(size_t)BH_*S_*DH_];
__device__ short g_kl[(size_t)BH_*S_*DH_];
__device__ short g_vt[(size_t)BH_*DH_*S_];

__device__ __forceinline__ short f2bf(float x){
  unsigned u = __builtin_bit_cast(unsigned, x);
  u += 0x7fffu + ((u >> 16) & 1u);           // RNE
  return (short)(unsigned short)(u >> 16);
}
__device__ __forceinline__ float bf2f(short h){
  return __builtin_bit_cast(float, ((unsigned)(unsigned short)h) << 16);
}

#define MFMA16(A,B,C) __builtin_amdgcn_mfma_f32_16x16x32_bf16((A),(B),(C),0,0,0)

// ---------------------------------------------------------------------------
// Pre-split f32 -> bf16 hi/lo (BW-bound, one pass)
// ---------------------------------------------------------------------------
__global__ __launch_bounds__(256) void split_f32(
    const float* __restrict__ src, short* __restrict__ dh,
    short* __restrict__ dl, int n8)
{
  int i = blockIdx.x * 256 + threadIdx.x;
  const int stride = gridDim.x * 256;
  for (; i < n8; i += stride) {
    float4 a = ((const float4*)src)[2*i];
    float4 b = ((const float4*)src)[2*i + 1];
    float f[8] = {a.x,a.y,a.z,a.w,b.x,b.y,b.z,b.w};
    short8v h, l;
#pragma unroll
    for (int j = 0; j < 8; ++j) {
      short hh = f2bf(f[j]);
      h[j] = hh;
      l[j] = f2bf(f[j] - bf2f(hh));
    }
    ((short8v*)dh)[i] = h;
    ((short8v*)dl)[i] = l;
  }
}

// ---------------------------------------------------------------------------
// QKV projection.  128x128 tile, 4 waves, BK=32. Inputs pre-split bf16.
// 3-term split MFMA for Q/K blocks, 1-term for V. Reg-prefetch next K-step.
// Epilogue re-stages C through LDS for coalesced 16B stores.
// ---------------------------------------------------------------------------
__global__ __launch_bounds__(256) void qkv_proj_mfma(const float* __restrict__ bias)
{
  __shared__ short SM[20480];   // 40 KB
  short (*AH )[40] = (short(*)[40])(SM);
  short (*AL )[40] = (short(*)[40])(SM + 5120);
  short (*BHs)[40] = (short(*)[40])(SM + 10240);
  short (*BLs)[40] = (short(*)[40])(SM + 15360);
  short *LT = SM;               // epilogue buffer, pitch 136

  const int tid = threadIdx.x;
  const int w  = tid >> 6;
  const int ln = tid & 15;
  const int g  = (tid & 63) >> 4;
  const int wr = w >> 1, wc = w & 1;
  const int m0 = blockIdx.y * 128;
  const int n0 = blockIdx.x * 128;
  const int which = n0 >> 10;       // 0=q 1=k 2=v

  const int r_  = tid >> 2;             // 0..63   (stage row, rep adds 64)
  const int c8  = (tid & 3) << 3;       // 0,8,16,24

  f32x4 zero4 = {0.f, 0.f, 0.f, 0.f};
  f32x4 acc[4][4];
#pragma unroll
  for (int mf = 0; mf < 4; ++mf)
#pragma unroll
    for (int nf = 0; nf < 4; ++nf) acc[mf][nf] = zero4;

  short8v rAh[2], rAl[2], rBh[2], rBl[2];
#pragma unroll
  for (int rep = 0; rep < 2; ++rep) {
    size_t ao = (size_t)(m0 + 64*rep + r_) * D_ + c8;
    size_t bo = (size_t)(n0 + 64*rep + r_) * D_ + c8;
    rAh[rep] = *(const short8v*)&g_xh[ao];
    rBh[rep] = *(const short8v*)&g_wh[bo];
    if (which < 2) {
      rAl[rep] = *(const short8v*)&g_xl[ao];
      rBl[rep] = *(const short8v*)&g_wl[bo];
    }
  }

  for (int k0 = 0; k0 < D_; k0 += 32) {
#pragma unroll
    for (int rep = 0; rep < 2; ++rep) {
      int r = 64*rep + r_;
      *(short8v*)&AH [r][c8] = rAh[rep];
      *(short8v*)&BHs[r][c8] = rBh[rep];
      if (which < 2) {
        *(short8v*)&AL [r][c8] = rAl[rep];
        *(short8v*)&BLs[r][c8] = rBl[rep];
      }
    }
    __syncthreads();

    if (k0 + 32 < D_) {
#pragma unroll
      for (int rep = 0; rep < 2; ++rep) {
        size_t ao = (size_t)(m0 + 64*rep + r_) * D_ + k0 + 32 + c8;
        size_t bo = (size_t)(n0 + 64*rep + r_) * D_ + k0 + 32 + c8;
        rAh[rep] = *(const short8v*)&g_xh[ao];
        rBh[rep] = *(const short8v*)&g_wh[bo];
        if (which < 2) {
          rAl[rep] = *(const short8v*)&g_xl[ao];
          rBl[rep] = *(const short8v*)&g_wl[bo];
        }
      }
    }

    short8v ah[4], al[4], bhf[4], blf[4];
#pragma unroll
    for (int mf = 0; mf < 4; ++mf) {
      ah[mf] = *(const short8v*)&AH[64*wr + 16*mf + ln][8*g];
      if (which < 2) al[mf] = *(const short8v*)&AL[64*wr + 16*mf + ln][8*g];
    }
#pragma unroll
    for (int nf = 0; nf < 4; ++nf) {
      bhf[nf] = *(const short8v*)&BHs[64*wc + 16*nf + ln][8*g];
      if (which < 2) blf[nf] = *(const short8v*)&BLs[64*wc + 16*nf + ln][8*g];
    }
    __builtin_amdgcn_s_setprio(1);
#pragma unroll
    for (int mf = 0; mf < 4; ++mf)
#pragma unroll
      for (int nf = 0; nf < 4; ++nf) {
        acc[mf][nf] = MFMA16(ah[mf], bhf[nf], acc[mf][nf]);
        if (which < 2) {
          acc[mf][nf] = MFMA16(al[mf], bhf[nf], acc[mf][nf]);
          acc[mf][nf] = MFMA16(ah[mf], blf[nf], acc[mf][nf]);
        }
      }
    __builtin_amdgcn_s_setprio(0);
    __syncthreads();
  }

  // ---- epilogue: bias+scale, then LDS-transpose coalesced stores ----
  const float sc = (which == 0) ? QSCALE : 1.0f;
  float bb[4];
#pragma unroll
  for (int nf = 0; nf < 4; ++nf) bb[nf] = bias[n0 + 64*wc + 16*nf + ln];
#pragma unroll
  for (int mf = 0; mf < 4; ++mf)
#pragma unroll
    for (int nf = 0; nf < 4; ++nf)
#pragma unroll
      for (int i = 0; i < 4; ++i)
        acc[mf][nf][i] = (acc[mf][nf][i] + bb[nf]) * sc;

  const int bidx  = m0 >> 11;
  const int s0    = m0 & 2047;
  const int hbase = (n0 & 1023) >> 6;

  if (which == 2) {
#pragma unroll
    for (int nf = 0; nf < 4; ++nf) {
      int dl = 64*wc + 16*nf + ln;
#pragma unroll
      for (int mf = 0; mf < 4; ++mf) {
        int sl = 64*wr + 16*mf + 4*g;
        short4v v4;
#pragma unroll
        for (int i = 0; i < 4; ++i) v4[i] = f2bf(acc[mf][nf][i]);
        *(short4v*)&LT[dl*136 + sl] = v4;
      }
    }
    __syncthreads();
#pragma unroll
    for (int rep = 0; rep < 8; ++rep) {
      int idx = rep * 256 + tid;
      int r  = idx >> 4;
      int sg = idx & 15;
      short8v v = *(const short8v*)&LT[r*136 + sg*8];
      int h = hbase + (r >> 6), dh = r & 63;
      *(short8v*)&g_vt[(((size_t)(bidx*H_ + h))*DH_ + dh)*S_ + s0 + sg*8] = v;
    }
  } else {
    short* dH = (which == 0) ? g_qh : g_kh;
    short* dL = (which == 0) ? g_ql : g_kl;
#pragma unroll
    for (int mf = 0; mf < 4; ++mf)
#pragma unroll
      for (int nf = 0; nf < 4; ++nf) {
        int dl = 64*wc + 16*nf + ln;
#pragma unroll
        for (int i = 0; i < 4; ++i)
          LT[(64*wr + 16*mf + 4*g + i)*136 + dl] = f2bf(acc[mf][nf][i]);
      }
    __syncthreads();
#pragma unroll
    for (int rep = 0; rep < 8; ++rep) {
      int idx = rep * 256 + tid;
      int r  = idx >> 4;
      int sg = idx & 15;
      short8v v = *(const short8v*)&LT[r*136 + sg*8];
      int h = hbase + (sg >> 3);
      int dh = (sg & 7) * 8;
      *(short8v*)&dH[(((size_t)(bidx*H_ + h))*S_ + s0 + r)*DH_ + dh] = v;
    }
    __syncthreads();
#pragma unroll
    for (int mf = 0; mf < 4; ++mf)
#pragma unroll
      for (int nf = 0; nf < 4; ++nf) {
        int dl = 64*wc + 16*nf + ln;
#pragma unroll
        for (int i = 0; i < 4; ++i) {
          float v = acc[mf][nf][i];
          short hi = f2bf(v);
          LT[(64*wr + 16*mf + 4*g + i)*136 + dl] = f2bf(v - bf2f(hi));
        }
      }
    __syncthreads();
#pragma unroll
    for (int rep = 0; rep < 8; ++rep) {
      int idx = rep * 256 + tid;
      int r  = idx >> 4;
      int sg = idx & 15;
      short8v v = *(const short8v*)&LT[r*136 + sg*8];
      int h = hbase + (sg >> 3);
      int dh = (sg & 7) * 8;
      *(short8v*)&dL[(((size_t)(bidx*H_ + h))*S_ + s0 + r)*DH_ + dh] = v;
    }
  }
}

// ---------------------------------------------------------------------------
// Flash attention. Block = 64 q-rows x (b,h); 4 waves x 16 rows; no barriers.
// Grid 1024 -> 4 blocks/CU at <=128 VGPR (KV-tile shrunk to 32 keys so the
// per-tile register set fits the launch_bounds(256,4) cap WITHOUT spilling).
// exp2-domain softmax with defer-rescale; K/V direct from global (L2-resident).
// ---------------------------------------------------------------------------
__global__ __launch_bounds__(256, 4) void attn_mfma(float* __restrict__ out)
{
  __shared__ short PS[4][16][64];   // per-wave; rows padded to 64, XOR-swizzled

  const int tid = threadIdx.x;
  const int w  = tid >> 6;
  const int ln = tid & 15;
  const int g  = (tid & 63) >> 4;

  // XCD-chunked swizzle: 1024 blocks; XCD x gets bh in [4x,4x+4).
  const int bid = blockIdx.x;
  const int swz = (bid & 7) * 128 + (bid >> 3);
  const int bh  = swz >> 5;
  const int q0  = (swz & 31) * 64;
  const int b   = bh >> 4, h = bh & 15;

  const size_t qb = (size_t)bh * S_ * DH_;
  const short* __restrict__ Kh = g_kh + qb;
  const short* __restrict__ Kl = g_kl + qb;
  const short* __restrict__ Vt = g_vt + (size_t)bh * DH_ * S_;

  // Q fragments: rows q0+16w+ln, k-slots d = 32ks+8g+j.
  short8v qh[2], ql[2];
#pragma unroll
  for (int ks = 0; ks < 2; ++ks) {
    size_t o = qb + (size_t)(q0 + 16*w + ln) * DH_ + 32*ks + 8*g;
    qh[ks] = *(const short8v*)&g_qh[o];
    ql[ks] = *(const short8v*)&g_ql[o];
  }

  f32x4 zero4 = {0.f,0.f,0.f,0.f};
  f32x4 o_[4];
  float m_[4], l_[4];
#pragma unroll
  for (int nf = 0; nf < 4; ++nf) o_[nf] = zero4;
#pragma unroll
  for (int i = 0; i < 4; ++i) { m_[i] = -1e30f; l_[i] = 0.f; }

  for (int t = 0; t < NKV_; ++t) {
    const int t0 = t * 32;

    // ---- K fragments (hi/lo): 32 keys = 2 nf frags, 2 ks halves ----
    short8v kh[2][2], kl[2][2];
#pragma unroll
    for (int ks = 0; ks < 2; ++ks)
#pragma unroll
      for (int nf = 0; nf < 2; ++nf) {
        size_t o = (size_t)(t0 + 16*nf + ln) * DH_ + 32*ks + 8*g;
        kh[ks][nf] = *(const short8v*)&Kh[o];
        kl[ks][nf] = *(const short8v*)&Kl[o];
      }

    // ---- S = Q K^T (scale folded into Q), 3-term split ----
    f32x4 s[2];
#pragma unroll
    for (int nf = 0; nf < 2; ++nf) s[nf] = zero4;
    __builtin_amdgcn_s_setprio(1);
#pragma unroll
    for (int ks = 0; ks < 2; ++ks)
#pragma unroll
      for (int nf = 0; nf < 2; ++nf) {
        s[nf] = MFMA16(qh[ks], kh[ks][nf], s[nf]);
        s[nf] = MFMA16(ql[ks], kh[ks][nf], s[nf]);
        s[nf] = MFMA16(qh[ks], kl[ks][nf], s[nf]);
      }
    __builtin_amdgcn_s_setprio(0);

    // ---- V fragments (issued before softmax; latency hides under VALU) ----
    // B-frag for PV: col = dh = 16nf+ln, k = key = 8g+j  (k-dim = 32 keys)
    short8v vb[4];
#pragma unroll
    for (int nf = 0; nf < 4; ++nf)
      vb[nf] = *(const short8v*)&Vt[(size_t)(16*nf + ln) * S_ + t0 + 8*g];

    // ---- online softmax (exp2 domain), defer-rescale ----
    float mt[4];
#pragma unroll
    for (int i = 0; i < 4; ++i) {
      float v = fmaxf(s[0][i], s[1][i]);
      v = fmaxf(v, __shfl_xor(v, 1));
      v = fmaxf(v, __shfl_xor(v, 2));
      v = fmaxf(v, __shfl_xor(v, 4));
      v = fmaxf(v, __shfl_xor(v, 8));
      mt[i] = v;
    }
    bool need = (mt[0] > m_[0]) | (mt[1] > m_[1]) |
                (mt[2] > m_[2]) | (mt[3] > m_[3]);
    if (__any(need)) {
#pragma unroll
      for (int i = 0; i < 4; ++i) {
        float mn = fmaxf(m_[i], mt[i]);
        float corr = exp2f(m_[i] - mn);
        l_[i] *= corr;
        m_[i] = mn;
#pragma unroll
        for (int nf = 0; nf < 4; ++nf) o_[nf][i] *= corr;
      }
    }
#pragma unroll
    for (int i = 0; i < 4; ++i) {
      float sum = 0.f;
      const int row = 4*g + i;
      const int e   = row & 7;
#pragma unroll
      for (int nf = 0; nf < 2; ++nf) {
        float p = exp2f(s[nf][i] - m_[i]);
        sum += p;
        PS[w][row][(16*nf + ln) ^ (e << 3)] = f2bf(p);
      }
      sum += __shfl_xor(sum, 1);
      sum += __shfl_xor(sum, 2);
      sum += __shfl_xor(sum, 4);
      sum += __shfl_xor(sum, 8);
      l_[i] += sum;
    }

    // ---- O += P V  (single k=32 MFMA per output frag) ----
    const short8v pa =
        *(const short8v*)&PS[w][ln][(8*g) ^ ((ln & 7) << 3)];
    __builtin_amdgcn_s_setprio(1);
#pragma unroll
    for (int nf = 0; nf < 4; ++nf)
      o_[nf] = MFMA16(pa, vb[nf], o_[nf]);
    __builtin_amdgcn_s_setprio(0);
  }

  // ---- epilogue ----
#pragma unroll
  for (int i = 0; i < 4; ++i) {
    float inv = 1.0f / l_[i];
    int row = q0 + 16*w + 4*g + i;
    float* op = &out[((size_t)b * S_ + row) * D_ + h * DH_];
#pragma unroll
    for (int nf = 0; nf < 4; ++nf)
      op[16*nf + ln] = o_[nf][i] * inv;
  }
}

extern "C" void kernel_launch(void* const* d_in, const int* in_sizes, int n_in,
                              void* d_out, int out_size, void* d_ws, size_t ws_size,
                              hipStream_t stream) {
    (void)d_ws; (void)ws_size; (void)n_in; (void)in_sizes;
    const float* X    = (const float*)d_in[0];  // query [B,S,D]
    const float* W    = (const float*)d_in[3];  // [3D, D]
    const float* bias = (const float*)d_in[4];  // [3D]
    float* out = (float*)d_out;

    short *xh, *xl, *wh, *wl;
    hipGetSymbolAddress((void**)&xh, HIP_SYMBOL(g_xh));
    hipGetSymbolAddress((void**)&xl, HIP_SYMBOL(g_xl));
    hipGetSymbolAddress((void**)&wh, HIP_SYMBOL(g_wh));
    hipGetSymbolAddress((void**)&wl, HIP_SYMBOL(g_wl));

    split_f32<<<dim3(1024), 256, 0, stream>>>(X, xh, xl, (B_*S_*D_)/8);
    split_f32<<<dim3(1024), 256, 0, stream>>>(W, wh, wl, (3*D_*D_)/8);

    dim3 gProj(24, 32);        // N/128 x M/128
    qkv_proj_mfma<<<gProj, 256, 0, stream>>>(bias);

    attn_mfma<<<dim3(1024), 256, 0, stream>>>(out);
}

// Round 7
// 336.748 us; speedup vs baseline: 1.8203x; 1.4547x over previous
//
#include <hip/hip_runtime.h>

#define B_  2
#define S_  2048
#define D_  1024
#define H_  16
#define DH_ 64
#define BH_ (B_*H_)
#define QSCALE 46.1662413084f   /* 32 * log2(e): exp2-domain softmax */

using f32x4   = __attribute__((ext_vector_type(4))) float;
using short4v = __attribute__((ext_vector_type(4))) short;
using short8v = __attribute__((ext_vector_type(8))) short;

// Pre-split inputs (bf16 hi/lo)
__device__ short g_xh[(size_t)B_*S_*D_], g_xl[(size_t)B_*S_*D_];
__device__ short g_wh[(size_t)3*D_*D_],  g_wl[(size_t)3*D_*D_];
// Proj outputs: q*QSCALE and k pre-split hi/lo [bh][s][dh]; v transposed [bh][dh][s].
__device__ short g_qh[(size_t)BH_*S_*DH_];
__device__ short g_ql[(size_t)BH_*S_*DH_];
__device__ short g_kh[(size_t)BH_*S_*DH_];
__device__ short g_kl[(size_t)BH_*S_*DH_];
__device__ short g_vt[(size_t)BH_*DH_*S_];

__device__ __forceinline__ short f2bf(float x){
  unsigned u = __builtin_bit_cast(unsigned, x);
  u += 0x7fffu + ((u >> 16) & 1u);           // RNE
  return (short)(unsigned short)(u >> 16);
}
__device__ __forceinline__ float bf2f(short h){
  return __builtin_bit_cast(float, ((unsigned)(unsigned short)h) << 16);
}

#define MFMA16(A,B,C) __builtin_amdgcn_mfma_f32_16x16x32_bf16((A),(B),(C),0,0,0)

// ---------------------------------------------------------------------------
// Pre-split f32 -> bf16 hi/lo (BW-bound, one pass)
// ---------------------------------------------------------------------------
__global__ __launch_bounds__(256) void split_f32(
    const float* __restrict__ src, short* __restrict__ dh,
    short* __restrict__ dl, int n8)
{
  int i = blockIdx.x * 256 + threadIdx.x;
  const int stride = gridDim.x * 256;
  for (; i < n8; i += stride) {
    float4 a = ((const float4*)src)[2*i];
    float4 b = ((const float4*)src)[2*i + 1];
    float f[8] = {a.x,a.y,a.z,a.w,b.x,b.y,b.z,b.w};
    short8v h, l;
#pragma unroll
    for (int j = 0; j < 8; ++j) {
      short hh = f2bf(f[j]);
      h[j] = hh;
      l[j] = f2bf(f[j] - bf2f(hh));
    }
    ((short8v*)dh)[i] = h;
    ((short8v*)dl)[i] = l;
  }
}

// ---------------------------------------------------------------------------
// QKV projection.  128x128 tile, 4 waves, BK=32. Inputs pre-split bf16.
// 3-term split MFMA for Q/K blocks, 1-term for V. Reg-prefetch next K-step.
// Epilogue re-stages C through LDS for coalesced 16B stores.
// ---------------------------------------------------------------------------
__global__ __launch_bounds__(256) void qkv_proj_mfma(const float* __restrict__ bias)
{
  __shared__ short SM[20480];   // 40 KB
  short (*AH )[40] = (short(*)[40])(SM);
  short (*AL )[40] = (short(*)[40])(SM + 5120);
  short (*BHs)[40] = (short(*)[40])(SM + 10240);
  short (*BLs)[40] = (short(*)[40])(SM + 15360);
  short *LT = SM;               // epilogue buffer, pitch 136

  const int tid = threadIdx.x;
  const int w  = tid >> 6;
  const int ln = tid & 15;
  const int g  = (tid & 63) >> 4;
  const int wr = w >> 1, wc = w & 1;
  const int m0 = blockIdx.y * 128;
  const int n0 = blockIdx.x * 128;
  const int which = n0 >> 10;       // 0=q 1=k 2=v

  const int r_  = tid >> 2;             // 0..63   (stage row, rep adds 64)
  const int c8  = (tid & 3) << 3;       // 0,8,16,24

  f32x4 zero4 = {0.f, 0.f, 0.f, 0.f};
  f32x4 acc[4][4];
#pragma unroll
  for (int mf = 0; mf < 4; ++mf)
#pragma unroll
    for (int nf = 0; nf < 4; ++nf) acc[mf][nf] = zero4;

  short8v rAh[2], rAl[2], rBh[2], rBl[2];
#pragma unroll
  for (int rep = 0; rep < 2; ++rep) {
    size_t ao = (size_t)(m0 + 64*rep + r_) * D_ + c8;
    size_t bo = (size_t)(n0 + 64*rep + r_) * D_ + c8;
    rAh[rep] = *(const short8v*)&g_xh[ao];
    rBh[rep] = *(const short8v*)&g_wh[bo];
    if (which < 2) {
      rAl[rep] = *(const short8v*)&g_xl[ao];
      rBl[rep] = *(const short8v*)&g_wl[bo];
    }
  }

  for (int k0 = 0; k0 < D_; k0 += 32) {
#pragma unroll
    for (int rep = 0; rep < 2; ++rep) {
      int r = 64*rep + r_;
      *(short8v*)&AH [r][c8] = rAh[rep];
      *(short8v*)&BHs[r][c8] = rBh[rep];
      if (which < 2) {
        *(short8v*)&AL [r][c8] = rAl[rep];
        *(short8v*)&BLs[r][c8] = rBl[rep];
      }
    }
    __syncthreads();

    if (k0 + 32 < D_) {
#pragma unroll
      for (int rep = 0; rep < 2; ++rep) {
        size_t ao = (size_t)(m0 + 64*rep + r_) * D_ + k0 + 32 + c8;
        size_t bo = (size_t)(n0 + 64*rep + r_) * D_ + k0 + 32 + c8;
        rAh[rep] = *(const short8v*)&g_xh[ao];
        rBh[rep] = *(const short8v*)&g_wh[bo];
        if (which < 2) {
          rAl[rep] = *(const short8v*)&g_xl[ao];
          rBl[rep] = *(const short8v*)&g_wl[bo];
        }
      }
    }

    short8v ah[4], al[4], bhf[4], blf[4];
#pragma unroll
    for (int mf = 0; mf < 4; ++mf) {
      ah[mf] = *(const short8v*)&AH[64*wr + 16*mf + ln][8*g];
      if (which < 2) al[mf] = *(const short8v*)&AL[64*wr + 16*mf + ln][8*g];
    }
#pragma unroll
    for (int nf = 0; nf < 4; ++nf) {
      bhf[nf] = *(const short8v*)&BHs[64*wc + 16*nf + ln][8*g];
      if (which < 2) blf[nf] = *(const short8v*)&BLs[64*wc + 16*nf + ln][8*g];
    }
    __builtin_amdgcn_s_setprio(1);
#pragma unroll
    for (int mf = 0; mf < 4; ++mf)
#pragma unroll
      for (int nf = 0; nf < 4; ++nf) {
        acc[mf][nf] = MFMA16(ah[mf], bhf[nf], acc[mf][nf]);
        if (which < 2) {
          acc[mf][nf] = MFMA16(al[mf], bhf[nf], acc[mf][nf]);
          acc[mf][nf] = MFMA16(ah[mf], blf[nf], acc[mf][nf]);
        }
      }
    __builtin_amdgcn_s_setprio(0);
    __syncthreads();
  }

  // ---- epilogue: bias+scale, then LDS-transpose coalesced stores ----
  const float sc = (which == 0) ? QSCALE : 1.0f;
  float bb[4];
#pragma unroll
  for (int nf = 0; nf < 4; ++nf) bb[nf] = bias[n0 + 64*wc + 16*nf + ln];
#pragma unroll
  for (int mf = 0; mf < 4; ++mf)
#pragma unroll
    for (int nf = 0; nf < 4; ++nf)
#pragma unroll
      for (int i = 0; i < 4; ++i)
        acc[mf][nf][i] = (acc[mf][nf][i] + bb[nf]) * sc;

  const int bidx  = m0 >> 11;
  const int s0    = m0 & 2047;
  const int hbase = (n0 & 1023) >> 6;

  if (which == 2) {
#pragma unroll
    for (int nf = 0; nf < 4; ++nf) {
      int dl = 64*wc + 16*nf + ln;
#pragma unroll
      for (int mf = 0; mf < 4; ++mf) {
        int sl = 64*wr + 16*mf + 4*g;
        short4v v4;
#pragma unroll
        for (int i = 0; i < 4; ++i) v4[i] = f2bf(acc[mf][nf][i]);
        *(short4v*)&LT[dl*136 + sl] = v4;
      }
    }
    __syncthreads();
#pragma unroll
    for (int rep = 0; rep < 8; ++rep) {
      int idx = rep * 256 + tid;
      int r  = idx >> 4;
      int sg = idx & 15;
      short8v v = *(const short8v*)&LT[r*136 + sg*8];
      int h = hbase + (r >> 6), dh = r & 63;
      *(short8v*)&g_vt[(((size_t)(bidx*H_ + h))*DH_ + dh)*S_ + s0 + sg*8] = v;
    }
  } else {
    short* dH = (which == 0) ? g_qh : g_kh;
    short* dL = (which == 0) ? g_ql : g_kl;
#pragma unroll
    for (int mf = 0; mf < 4; ++mf)
#pragma unroll
      for (int nf = 0; nf < 4; ++nf) {
        int dl = 64*wc + 16*nf + ln;
#pragma unroll
        for (int i = 0; i < 4; ++i)
          LT[(64*wr + 16*mf + 4*g + i)*136 + dl] = f2bf(acc[mf][nf][i]);
      }
    __syncthreads();
#pragma unroll
    for (int rep = 0; rep < 8; ++rep) {
      int idx = rep * 256 + tid;
      int r  = idx >> 4;
      int sg = idx & 15;
      short8v v = *(const short8v*)&LT[r*136 + sg*8];
      int h = hbase + (sg >> 3);
      int dh = (sg & 7) * 8;
      *(short8v*)&dH[(((size_t)(bidx*H_ + h))*S_ + s0 + r)*DH_ + dh] = v;
    }
    __syncthreads();
#pragma unroll
    for (int mf = 0; mf < 4; ++mf)
#pragma unroll
      for (int nf = 0; nf < 4; ++nf) {
        int dl = 64*wc + 16*nf + ln;
#pragma unroll
        for (int i = 0; i < 4; ++i) {
          float v = acc[mf][nf][i];
          short hi = f2bf(v);
          LT[(64*wr + 16*mf + 4*g + i)*136 + dl] = f2bf(v - bf2f(hi));
        }
      }
    __syncthreads();
#pragma unroll
    for (int rep = 0; rep < 8; ++rep) {
      int idx = rep * 256 + tid;
      int r  = idx >> 4;
      int sg = idx & 15;
      short8v v = *(const short8v*)&LT[r*136 + sg*8];
      int h = hbase + (sg >> 3);
      int dh = (sg & 7) * 8;
      *(short8v*)&dL[(((size_t)(bidx*H_ + h))*S_ + s0 + r)*DH_ + dh] = v;
    }
  }
}

// ---------------------------------------------------------------------------
// Flash attention, split-KV inside the block.
// Block = 512 threads (8 waves) x 128 q-rows x (b,h). Wave-group sp=w>>2
// handles keys [sp*1024, sp*1024+1024); each wave keeps the r4 structure:
// 32 q-rows, 64-key tiles, K/V frags direct from global, no in-loop barriers.
// End: group 1 publishes (o,m,l) via reused PS LDS; group 0 merges + writes.
// ---------------------------------------------------------------------------
__global__ __launch_bounds__(512, 2) void attn_mfma(float* __restrict__ out)
{
  __shared__ short PS[8][32][64];   // per-wave P staging; reused as f32 merge buf
  __shared__ float MM[4][32], LL[4][32];

  const int tid = threadIdx.x;
  const int w   = tid >> 6;         // 0..7
  const int sp  = w >> 2;           // key-split group
  const int w4  = w & 3;            // row-group within split
  const int lane = tid & 63;
  const int ln  = tid & 15;
  const int g   = (tid & 63) >> 4;

  // XCD-chunked swizzle: 512 blocks; XCD x gets bh in [4x,4x+4).
  const int bid = blockIdx.x;
  const int swz = (bid & 7) * 64 + (bid >> 3);
  const int bh  = swz >> 4;
  const int q0  = (swz & 15) * 128;
  const int b   = bh >> 4, h = bh & 15;

  const size_t qb = (size_t)bh * S_ * DH_;
  const short* __restrict__ Kh = g_kh + qb;
  const short* __restrict__ Kl = g_kl + qb;
  const short* __restrict__ Vt = g_vt + (size_t)bh * DH_ * S_;

  // Q fragments: rows q0+32w4+16rf+ln, k-slots d = 32ks+8g+j.
  short8v qh[2][2], ql[2][2];
#pragma unroll
  for (int rf = 0; rf < 2; ++rf)
#pragma unroll
    for (int ks = 0; ks < 2; ++ks) {
      size_t o = qb + (size_t)(q0 + 32*w4 + 16*rf + ln) * DH_ + 32*ks + 8*g;
      qh[rf][ks] = *(const short8v*)&g_qh[o];
      ql[rf][ks] = *(const short8v*)&g_ql[o];
    }

  f32x4 zero4 = {0.f,0.f,0.f,0.f};
  f32x4 o_[2][4];
  float m_[2][4], l_[2][4];
#pragma unroll
  for (int rf = 0; rf < 2; ++rf)
#pragma unroll
    for (int nf = 0; nf < 4; ++nf) o_[rf][nf] = zero4;
#pragma unroll
  for (int rf = 0; rf < 2; ++rf)
#pragma unroll
    for (int i = 0; i < 4; ++i) { m_[rf][i] = -1e30f; l_[rf][i] = 0.f; }

  for (int t = sp * 16; t < sp * 16 + 16; ++t) {
    const int t0 = t * 64;

    // ---- K fragments (hi/lo) ----
    short8v kh[2][4], kl[2][4];
#pragma unroll
    for (int ks = 0; ks < 2; ++ks)
#pragma unroll
      for (int nf = 0; nf < 4; ++nf) {
        size_t o = (size_t)(t0 + 16*nf + ln) * DH_ + 32*ks + 8*g;
        kh[ks][nf] = *(const short8v*)&Kh[o];
        kl[ks][nf] = *(const short8v*)&Kl[o];
      }

    // ---- S = Q K^T (scale folded into Q), 3-term split ----
    f32x4 s[2][4];
#pragma unroll
    for (int rf = 0; rf < 2; ++rf)
#pragma unroll
      for (int nf = 0; nf < 4; ++nf) s[rf][nf] = zero4;
    __builtin_amdgcn_s_setprio(1);
#pragma unroll
    for (int rf = 0; rf < 2; ++rf)
#pragma unroll
      for (int ks = 0; ks < 2; ++ks)
#pragma unroll
        for (int nf = 0; nf < 4; ++nf) {
          s[rf][nf] = MFMA16(qh[rf][ks], kh[ks][nf], s[rf][nf]);
          s[rf][nf] = MFMA16(ql[rf][ks], kh[ks][nf], s[rf][nf]);
          s[rf][nf] = MFMA16(qh[rf][ks], kl[ks][nf], s[rf][nf]);
        }
    __builtin_amdgcn_s_setprio(0);

    // ---- V fragments (issued before softmax; latency hides under VALU) ----
    short8v vb[2][4];
#pragma unroll
    for (int ks = 0; ks < 2; ++ks)
#pragma unroll
      for (int nf = 0; nf < 4; ++nf)
        vb[ks][nf] = *(const short8v*)&Vt[(size_t)(16*nf + ln) * S_ + t0 + 32*ks + 8*g];

    // ---- online softmax (exp2 domain), defer-rescale ----
    float mt[2][4];
#pragma unroll
    for (int rf = 0; rf < 2; ++rf)
#pragma unroll
      for (int i = 0; i < 4; ++i) {
        float v = fmaxf(fmaxf(s[rf][0][i], s[rf][1][i]),
                        fmaxf(s[rf][2][i], s[rf][3][i]));
        v = fmaxf(v, __shfl_xor(v, 1));
        v = fmaxf(v, __shfl_xor(v, 2));
        v = fmaxf(v, __shfl_xor(v, 4));
        v = fmaxf(v, __shfl_xor(v, 8));
        mt[rf][i] = v;
      }
    bool need = false;
#pragma unroll
    for (int rf = 0; rf < 2; ++rf)
#pragma unroll
      for (int i = 0; i < 4; ++i) need |= (mt[rf][i] > m_[rf][i]);
    if (__any(need)) {
#pragma unroll
      for (int rf = 0; rf < 2; ++rf)
#pragma unroll
        for (int i = 0; i < 4; ++i) {
          float mn = fmaxf(m_[rf][i], mt[rf][i]);
          float corr = exp2f(m_[rf][i] - mn);
          l_[rf][i] *= corr;
          m_[rf][i] = mn;
#pragma unroll
          for (int nf = 0; nf < 4; ++nf) o_[rf][nf][i] *= corr;
        }
    }
#pragma unroll
    for (int rf = 0; rf < 2; ++rf)
#pragma unroll
      for (int i = 0; i < 4; ++i) {
        float sum = 0.f;
        const int row = 16*rf + 4*g + i;
        const int e   = row & 7;
#pragma unroll
        for (int nf = 0; nf < 4; ++nf) {
          float p = exp2f(s[rf][nf][i] - m_[rf][i]);
          sum += p;
          PS[w][row][(16*nf + ln) ^ (e << 3)] = f2bf(p);
        }
        sum += __shfl_xor(sum, 1);
        sum += __shfl_xor(sum, 2);
        sum += __shfl_xor(sum, 4);
        sum += __shfl_xor(sum, 8);
        l_[rf][i] += sum;
      }

    // ---- O += P V ----
    __builtin_amdgcn_s_setprio(1);
#pragma unroll
    for (int rf = 0; rf < 2; ++rf)
#pragma unroll
      for (int ks = 0; ks < 2; ++ks) {
        const short8v pa =
            *(const short8v*)&PS[w][16*rf + ln][(32*ks + 8*g) ^ ((ln & 7) << 3)];
#pragma unroll
        for (int nf = 0; nf < 4; ++nf)
          o_[rf][nf] = MFMA16(pa, vb[ks][nf], o_[rf][nf]);
      }
    __builtin_amdgcn_s_setprio(0);
  }

  // ---- split-KV merge: group 1 publishes via LDS, group 0 merges+writes ----
  __syncthreads();
  float* MB = (float*)(&PS[0][0][0]);   // 8192 floats = exactly PS size
  if (sp == 1) {
#pragma unroll
    for (int rf = 0; rf < 2; ++rf)
#pragma unroll
      for (int i = 0; i < 4; ++i)
        if (ln == 0) {
          MM[w4][16*rf + 4*g + i] = m_[rf][i];
          LL[w4][16*rf + 4*g + i] = l_[rf][i];
        }
#pragma unroll
    for (int rf = 0; rf < 2; ++rf)
#pragma unroll
      for (int nf = 0; nf < 4; ++nf)
#pragma unroll
        for (int i = 0; i < 4; ++i)
          MB[(w4*64 + lane)*32 + rf*16 + nf*4 + i] = o_[rf][nf][i];
  }
  __syncthreads();
  if (sp == 0) {
#pragma unroll
    for (int rf = 0; rf < 2; ++rf)
#pragma unroll
      for (int i = 0; i < 4; ++i) {
        const int rloc = 16*rf + 4*g + i;
        float m2 = MM[w4][rloc], l2 = LL[w4][rloc];
        float ms = fmaxf(m_[rf][i], m2);
        float c1 = exp2f(m_[rf][i] - ms);
        float c2 = exp2f(m2 - ms);
        float inv = 1.0f / (l_[rf][i] * c1 + l2 * c2);
        int row = q0 + 32*w4 + rloc;
        float* op = &out[((size_t)b * S_ + row) * D_ + h * DH_];
#pragma unroll
        for (int nf = 0; nf < 4; ++nf) {
          float o2v = MB[(w4*64 + lane)*32 + rf*16 + nf*4 + i];
          op[16*nf + ln] = (o_[rf][nf][i] * c1 + o2v * c2) * inv;
        }
      }
  }
}

extern "C" void kernel_launch(void* const* d_in, const int* in_sizes, int n_in,
                              void* d_out, int out_size, void* d_ws, size_t ws_size,
                              hipStream_t stream) {
    (void)d_ws; (void)ws_size; (void)n_in; (void)in_sizes;
    const float* X    = (const float*)d_in[0];  // query [B,S,D]
    const float* W    = (const float*)d_in[3];  // [3D, D]
    const float* bias = (const float*)d_in[4];  // [3D]
    float* out = (float*)d_out;

    short *xh, *xl, *wh, *wl;
    hipGetSymbolAddress((void**)&xh, HIP_SYMBOL(g_xh));
    hipGetSymbolAddress((void**)&xl, HIP_SYMBOL(g_xl));
    hipGetSymbolAddress((void**)&wh, HIP_SYMBOL(g_wh));
    hipGetSymbolAddress((void**)&wl, HIP_SYMBOL(g_wl));

    split_f32<<<dim3(1024), 256, 0, stream>>>(X, xh, xl, (B_*S_*D_)/8);
    split_f32<<<dim3(1024), 256, 0, stream>>>(W, wh, wl, (3*D_*D_)/8);

    dim3 gProj(24, 32);        // N/128 x M/128
    qkv_proj_mfma<<<gProj, 256, 0, stream>>>(bias);

    attn_mfma<<<dim3(512), 512, 0, stream>>>(out);
}